// Round 1
// baseline (306.526 us; speedup 1.0000x reference)
//
#include <hip/hip_runtime.h>
#include <stdint.h>

// Fused 2x tiny-LSTM (H=1) over T=512, B=4096, F=25 (12+13 split) + sigmoid head.
// Design: 512 blocks x 64 threads (1 wave/block, 8 chains/block, 8 lanes/chain).
//  - global_load_lds staging of x tiles (16 timesteps), double buffered
//  - GEMV phase: all 64 lanes compute gate preactivations z[8] per (chain,t)
//  - scan phase: lanes redundantly run the serial LSTM recurrence from z-tile
//  - scan(k) and GEMV(k+1) share one basic block so the scheduler interleaves.

#define T_STEPS 512
#define F_IN    25
#define TC      16
#define NTILES  (T_STEPS / TC)     // 32
#define CH      8                  // chains (batch elems) per block
#define XROW    520                // padded floats per chain per x tile (400 data + pad)
                                   // 520 % 32 == 8 -> perfect bank spread for b32 reads
#define ZROW    (TC * 8 + 8)       // 136; 136 % 32 == 8 -> 2-way (free) for b128 reads
#define LOG2E   1.44269504088896340736f

typedef const __attribute__((address_space(1))) void* as1_cvp;
typedef __attribute__((address_space(3)))       void* as3_vp;

__device__ __forceinline__ void gll16(const float* gsrc, const float* ldst) {
  // async global->LDS, 16 B/lane. LDS dst is wave-uniform base + lane*16.
  __builtin_amdgcn_global_load_lds((as1_cvp)(uintptr_t)gsrc,
                                   (as3_vp)(uint32_t)(uintptr_t)ldst, 16, 0, 0);
}

__device__ __forceinline__ float sigm(float v) {
  return __builtin_amdgcn_rcpf(1.0f + __builtin_amdgcn_exp2f(v * (-LOG2E)));
}
__device__ __forceinline__ float tanh_(float v) {
  // tanh(x) = 2*sigmoid(2x) - 1
  return fmaf(2.0f, __builtin_amdgcn_rcpf(1.0f + __builtin_amdgcn_exp2f(v * (-2.0f * LOG2E))), -1.0f);
}

__device__ __forceinline__ void prefetch_tile(const float* __restrict__ x, int b0, int tile,
                                              float* xbuf, int lane) {
  // per chain: 400 contiguous floats (16 timesteps x 25) -> 2 GLL dwordx4 insts
  const float* base = x + (size_t)b0 * (T_STEPS * F_IN) + tile * (TC * F_IN);
  const int i1 = lane * 4;          // floats 0..255
  int i2 = 256 + lane * 4;          // floats 256..399 (+pad lanes clamped, harmless)
  if (i2 > 396) i2 = 396;
#pragma unroll
  for (int cc = 0; cc < CH; ++cc) {
    const float* g0 = base + cc * (T_STEPS * F_IN);
    gll16(g0 + i1, xbuf + cc * XROW);          // uniform LDS base per inst
    gll16(g0 + i2, xbuf + cc * XROW + 256);
  }
}

__device__ __forceinline__ void gemv_tile(const float* __restrict__ xbuf, float* __restrict__ zbuf,
                                          int c, int lt,
                                          const float* __restrict__ w1, const float* __restrict__ w2,
                                          const float* __restrict__ zb) {
  // lane (c, lt) handles timesteps lt and lt+8 of this tile: z[8] = W_ih . x + b
#pragma unroll
  for (int p = 0; p < 2; ++p) {
    const int tl = p * 8 + lt;
    const float* xr = xbuf + c * XROW + tl * F_IN;
    float z[8];
#pragma unroll
    for (int j = 0; j < 8; ++j) z[j] = zb[j];
#pragma unroll
    for (int f = 0; f < 12; ++f) {
      const float xv = xr[f];
#pragma unroll
      for (int j = 0; j < 4; ++j) z[j] = fmaf(w1[j * 12 + f], xv, z[j]);
    }
#pragma unroll
    for (int f = 0; f < 13; ++f) {
      const float xv = xr[12 + f];
#pragma unroll
      for (int j = 0; j < 4; ++j) z[4 + j] = fmaf(w2[j * 13 + f], xv, z[4 + j]);
    }
    float4* zp = (float4*)(zbuf + c * ZROW + tl * 8);
    zp[0] = make_float4(z[0], z[1], z[2], z[3]);
    zp[1] = make_float4(z[4], z[5], z[6], z[7]);
  }
}

__device__ __forceinline__ void scan_tile(const float* __restrict__ zbuf, int c, int zoff,
                                          const float* __restrict__ whh, float& hv, float& cv) {
  // every lane of the chain redundantly runs its LSTM (zoff 0 -> LSTM1, 4 -> LSTM2)
#pragma unroll
  for (int t = 0; t < TC; ++t) {
    const float4 z4 = *(const float4*)(zbuf + c * ZROW + t * 8 + zoff);
    const float pi = fmaf(hv, whh[0], z4.x);
    const float pf = fmaf(hv, whh[1], z4.y);
    const float pg = fmaf(hv, whh[2], z4.z);
    const float po = fmaf(hv, whh[3], z4.w);
    const float ai = sigm(pi);
    const float af = sigm(pf);
    const float ag = tanh_(pg);
    const float ao = sigm(po);
    cv = fmaf(af, cv, ai * ag);
    hv = ao * tanh_(cv);
  }
}

__global__ void __launch_bounds__(64, 1)
lstm2_fused(const float* __restrict__ x,
            const float* __restrict__ Wih1, const float* __restrict__ Whh1, const float* __restrict__ b1,
            const float* __restrict__ Wih2, const float* __restrict__ Whh2, const float* __restrict__ b2,
            const float* __restrict__ Wout, const float* __restrict__ bout,
            float* __restrict__ out)
{
  __shared__ __align__(16) float xs0[CH * XROW];
  __shared__ __align__(16) float xs1[CH * XROW];
  __shared__ __align__(16) float zs0[CH * ZROW];
  __shared__ __align__(16) float zs1[CH * ZROW];

  const int lane = threadIdx.x;     // 0..63
  const int c    = lane >> 3;       // chain 0..7
  const int g    = lane & 7;        // sub-lane 0..7
  const int b0   = blockIdx.x * CH;
  const int zoff = g & 4;           // 0 -> LSTM1, 4 -> LSTM2

  float w1[48], w2[52], zb[8], whh[4];
#pragma unroll
  for (int j = 0; j < 48; ++j) w1[j] = Wih1[j];
#pragma unroll
  for (int j = 0; j < 52; ++j) w2[j] = Wih2[j];
#pragma unroll
  for (int j = 0; j < 4; ++j) { zb[j] = b1[j]; zb[4 + j] = b2[j]; }
#pragma unroll
  for (int j = 0; j < 4; ++j) whh[j] = (g < 4) ? Whh1[j] : Whh2[j];

  float hv = 0.0f, cv = 0.0f;

  // ---- pipeline prologue ----
  prefetch_tile(x, b0, 0, xs0, lane);
  asm volatile("s_waitcnt vmcnt(0)" ::: "memory");   // tile 0 staged
  prefetch_tile(x, b0, 1, xs1, lane);                // tile 1 in flight during GEMV(0)
  gemv_tile(xs0, zs0, c, g, w1, w2, zb);
  asm volatile("s_waitcnt lgkmcnt(0)" ::: "memory"); // z-tile 0 visible

  // ---- steady state: scan(k) interleaved with GEMV(k+1), prefetch(k+2) ----
  for (int k = 0; k < NTILES - 1; ++k) {
    asm volatile("s_waitcnt vmcnt(0)" ::: "memory"); // x tile k+1 staged
    int tn = k + 2;
    if (tn > NTILES - 1) tn = NTILES - 1;            // branchless tail (redundant, harmless)
    prefetch_tile(x, b0, tn, (k & 1) ? xs1 : xs0, lane);
    const float* zrd = (k & 1) ? zs1 : zs0;
    const float* xrd = (k & 1) ? xs0 : xs1;
    float*       zwr = (k & 1) ? zs0 : zs1;
    scan_tile(zrd, c, zoff, whh, hv, cv);            // latency-bound
    gemv_tile(xrd, zwr, c, g, w1, w2, zb);           // throughput-bound, fills stalls
    asm volatile("s_waitcnt lgkmcnt(0)" ::: "memory");
  }
  scan_tile(zs1, c, zoff, whh, hv, cv);              // tile 31 ((31&1)==1)

  // ---- head: out = sigmoid(W_out . [h1,h2] + b_out) ----
  const float h1 = __shfl(hv, (lane & 56) + 0, 64);
  const float h2 = __shfl(hv, (lane & 56) + 4, 64);
  if (g == 0) {
    out[b0 + c] = sigm(fmaf(Wout[0], h1, fmaf(Wout[1], h2, bout[0])));
  }
}

extern "C" void kernel_launch(void* const* d_in, const int* in_sizes, int n_in,
                              void* d_out, int out_size, void* d_ws, size_t ws_size,
                              hipStream_t stream) {
  const float* x    = (const float*)d_in[0];
  const float* Wih1 = (const float*)d_in[1];
  const float* Whh1 = (const float*)d_in[2];
  const float* b1   = (const float*)d_in[3];
  const float* Wih2 = (const float*)d_in[4];
  const float* Whh2 = (const float*)d_in[5];
  const float* b2   = (const float*)d_in[6];
  const float* Wout = (const float*)d_in[7];
  const float* bout = (const float*)d_in[8];
  float* out = (float*)d_out;

  const int B = in_sizes[0] / (T_STEPS * F_IN);      // 4096
  dim3 grid(B / CH), block(64);
  hipLaunchKernelGGL(lstm2_fused, grid, block, 0, stream,
                     x, Wih1, Whh1, b1, Wih2, Whh2, b2, Wout, bout, out);
}